// Round 2
// baseline (40.777 us; speedup 1.0000x reference)
//
#include <hip/hip_runtime.h>
#include <hip/hip_bf16.h>

// Problem constants (match reference)
#define BQ 4096
#define KN 64
#define LD 256

__global__ __launch_bounds__(256) void knn_weighted_gather_kernel(
    const float* __restrict__ sq_dists,       // [B, K]
    const int*   __restrict__ labels,         // [B, K]
    const float* __restrict__ exemplar_labels,// [N, L]
    const float* __restrict__ exemplar_sizes, // [N]
    const float* __restrict__ average_label,  // [L]
    const float* __restrict__ tau_squared_p,  // [1]
    const float* __restrict__ gamma_n_p,      // [1]
    float* __restrict__ out)                  // [B, L] f32
{
    __shared__ float s_w[KN];
    __shared__ int   s_lab[KN];
    __shared__ float s_denom;

    const int b   = blockIdx.x;
    const int tid = threadIdx.x;
    const float tau2    = tau_squared_p[0];
    const float gamma_n = gamma_n_p[0];

    // First wave (64 lanes) computes weights + denominator
    if (tid < KN) {
        float d   = sq_dists[b * KN + tid];
        int   lab = labels[b * KN + tid];
        float w   = (d <= tau2) ? __expf(-d) : 0.0f;
        s_w[tid]   = w;
        s_lab[tid] = lab;
        float dpart = w * exemplar_sizes[lab];
        // 64-lane butterfly reduce
        #pragma unroll
        for (int off = 32; off > 0; off >>= 1)
            dpart += __shfl_down(dpart, off, 64);
        if (tid == 0) s_denom = dpart;
    }
    __syncthreads();

    const int l = tid;            // each thread owns one output column
    float acc = 0.0f;
    #pragma unroll 4
    for (int k = 0; k < KN; ++k) {
        float w = s_w[k];         // LDS broadcast (uniform across lanes)
        if (w != 0.0f) {          // block-uniform branch: skip truncated rows
            acc += w * exemplar_labels[(size_t)s_lab[k] * LD + l];
        }
    }
    float res = (acc + gamma_n * average_label[l]) / (s_denom + gamma_n);
    out[(size_t)b * LD + l] = res;
}

extern "C" void kernel_launch(void* const* d_in, const int* in_sizes, int n_in,
                              void* d_out, int out_size, void* d_ws, size_t ws_size,
                              hipStream_t stream) {
    const float* sq_dists        = (const float*)d_in[0];
    const int*   labels          = (const int*)  d_in[1];
    const float* exemplar_labels = (const float*)d_in[2];
    const float* exemplar_sizes  = (const float*)d_in[3];
    const float* average_label   = (const float*)d_in[4];
    const float* tau_squared     = (const float*)d_in[5];
    const float* gamma_n         = (const float*)d_in[6];
    float* out = (float*)d_out;

    knn_weighted_gather_kernel<<<BQ, LD, 0, stream>>>(
        sq_dists, labels, exemplar_labels, exemplar_sizes, average_label,
        tau_squared, gamma_n, out);
}

// Round 3
// 28.068 us; speedup vs baseline: 1.4528x; 1.4528x over previous
//
#include <hip/hip_runtime.h>
#include <hip/hip_bf16.h>

// Problem constants (match reference)
#define BQ 4096
#define KN 64
#define LD 256
#define QPB 4   // queries per block = waves per block

__global__ __launch_bounds__(256) void knn_weighted_gather_kernel(
    const float* __restrict__ sq_dists,       // [B, K]
    const int*   __restrict__ labels,         // [B, K]
    const float* __restrict__ exemplar_labels,// [N, L]
    const float* __restrict__ exemplar_sizes, // [N]
    const float* __restrict__ average_label,  // [L]
    const float* __restrict__ tau_squared_p,  // [1]
    const float* __restrict__ gamma_n_p,      // [1]
    float* __restrict__ out)                  // [B, L] f32
{
    const int wave = threadIdx.x >> 6;
    const int lane = threadIdx.x & 63;
    const int q    = blockIdx.x * QPB + wave;   // one query per wave

    const float tau2    = tau_squared_p[0];
    const float gamma_n = gamma_n_p[0];

    // Lane k holds this query's (w[k], lab[k]) in registers. KN == 64 lanes.
    float d   = sq_dists[q * KN + lane];
    int   lab = labels  [q * KN + lane];
    float w   = (d <= tau2) ? __expf(-d) : 0.0f;

    // Denominator: butterfly reduce of w * sizes[lab] across the wave.
    float dpart = w * exemplar_sizes[lab];
    #pragma unroll
    for (int off = 32; off > 0; off >>= 1)
        dpart += __shfl_xor(dpart, off, 64);
    // dpart == full denominator sum in every lane now.

    // Gather: lane i owns columns 4i..4i+3 -> one float4 per row, coalesced.
    float4 acc = make_float4(0.f, 0.f, 0.f, 0.f);
    #pragma unroll 8
    for (int k = 0; k < KN; ++k) {
        float wk   = __shfl(w,   k, 64);   // register broadcast, no LDS/sync
        int   labk = __shfl(lab, k, 64);
        if (wk != 0.0f) {                  // wave-uniform skip of truncated rows
            const float4 v = *reinterpret_cast<const float4*>(
                exemplar_labels + (size_t)labk * LD + lane * 4);
            acc.x += wk * v.x;
            acc.y += wk * v.y;
            acc.z += wk * v.z;
            acc.w += wk * v.w;
        }
    }

    const float4 avg = *reinterpret_cast<const float4*>(average_label + lane * 4);
    const float inv = 1.0f / (dpart + gamma_n);
    float4 res;
    res.x = (acc.x + gamma_n * avg.x) * inv;
    res.y = (acc.y + gamma_n * avg.y) * inv;
    res.z = (acc.z + gamma_n * avg.z) * inv;
    res.w = (acc.w + gamma_n * avg.w) * inv;
    *reinterpret_cast<float4*>(out + (size_t)q * LD + lane * 4) = res;
}

extern "C" void kernel_launch(void* const* d_in, const int* in_sizes, int n_in,
                              void* d_out, int out_size, void* d_ws, size_t ws_size,
                              hipStream_t stream) {
    const float* sq_dists        = (const float*)d_in[0];
    const int*   labels          = (const int*)  d_in[1];
    const float* exemplar_labels = (const float*)d_in[2];
    const float* exemplar_sizes  = (const float*)d_in[3];
    const float* average_label   = (const float*)d_in[4];
    const float* tau_squared     = (const float*)d_in[5];
    const float* gamma_n         = (const float*)d_in[6];
    float* out = (float*)d_out;

    knn_weighted_gather_kernel<<<BQ / QPB, QPB * 64, 0, stream>>>(
        sq_dists, labels, exemplar_labels, exemplar_sizes, average_label,
        tau_squared, gamma_n, out);
}

// Round 4
// 27.296 us; speedup vs baseline: 1.4939x; 1.0283x over previous
//
#include <hip/hip_runtime.h>
#include <hip/hip_bf16.h>

// Problem constants (match reference)
#define BQ 4096
#define KN 64
#define LD 256
#define QPB 4   // queries per block = waves per block

__global__ __launch_bounds__(256) void knn_weighted_gather_kernel(
    const float* __restrict__ sq_dists,       // [B, K]
    const int*   __restrict__ labels,         // [B, K]
    const float* __restrict__ exemplar_labels,// [N, L]
    const float* __restrict__ exemplar_sizes, // [N]
    const float* __restrict__ average_label,  // [L]
    const float* __restrict__ tau_squared_p,  // [1]
    const float* __restrict__ gamma_n_p,      // [1]
    float* __restrict__ out)                  // [B, L] f32
{
    const int wave = threadIdx.x >> 6;
    const int lane = threadIdx.x & 63;
    const int q    = blockIdx.x * QPB + wave;   // one query per wave

    const float tau2    = tau_squared_p[0];
    const float gamma_n = gamma_n_p[0];

    // Lane k holds this query's (w[k], lab[k]) in registers. KN == 64 lanes.
    float d   = sq_dists[q * KN + lane];
    int   lab = labels  [q * KN + lane];
    float w   = (d <= tau2) ? __expf(-d) : 0.0f;

    // Denominator: butterfly reduce of w * sizes[lab] across the wave.
    float dpart = w * exemplar_sizes[lab];
    #pragma unroll
    for (int off = 32; off > 0; off >>= 1)
        dpart += __shfl_xor(dpart, off, 64);

    // Compact the active (w != 0) lanes into a scalar bitmask; walk set bits.
    // Body is branch-free -> all loads in an unrolled body stay in flight.
    unsigned long long mask = __ballot(w != 0.0f);
    const int nact = __popcll(mask);
    const int wbits = __float_as_int(w);
    const float* __restrict__ colbase = exemplar_labels + lane * 4;

    float4 acc = make_float4(0.f, 0.f, 0.f, 0.f);

#define STEP(SV, WV, LV, VV)                                          \
    int SV = (int)__builtin_ctzll(mask); mask &= mask - 1;            \
    float WV = __int_as_float(__builtin_amdgcn_readlane(wbits, SV));  \
    int LV = __builtin_amdgcn_readlane(lab, SV);                      \
    const float4 VV = *reinterpret_cast<const float4*>(colbase + (size_t)LV * LD)

#define FMA4(WV, VV)                                                  \
    acc.x += WV * VV.x; acc.y += WV * VV.y;                           \
    acc.z += WV * VV.z; acc.w += WV * VV.w

    int i = 0;
    for (; i + 8 <= nact; i += 8) {
        STEP(s0, w0, l0, v0); STEP(s1, w1, l1, v1);
        STEP(s2, w2, l2, v2); STEP(s3, w3, l3, v3);
        STEP(s4, w4, l4, v4); STEP(s5, w5, l5, v5);
        STEP(s6, w6, l6, v6); STEP(s7, w7, l7, v7);
        FMA4(w0, v0); FMA4(w1, v1); FMA4(w2, v2); FMA4(w3, v3);
        FMA4(w4, v4); FMA4(w5, v5); FMA4(w6, v6); FMA4(w7, v7);
    }
    for (; i < nact; ++i) {
        STEP(s0, w0, l0, v0);
        FMA4(w0, v0);
    }
#undef STEP
#undef FMA4

    const float4 avg = *reinterpret_cast<const float4*>(average_label + lane * 4);
    const float inv = 1.0f / (dpart + gamma_n);
    float4 res;
    res.x = (acc.x + gamma_n * avg.x) * inv;
    res.y = (acc.y + gamma_n * avg.y) * inv;
    res.z = (acc.z + gamma_n * avg.z) * inv;
    res.w = (acc.w + gamma_n * avg.w) * inv;
    *reinterpret_cast<float4*>(out + (size_t)q * LD + lane * 4) = res;
}

extern "C" void kernel_launch(void* const* d_in, const int* in_sizes, int n_in,
                              void* d_out, int out_size, void* d_ws, size_t ws_size,
                              hipStream_t stream) {
    const float* sq_dists        = (const float*)d_in[0];
    const int*   labels          = (const int*)  d_in[1];
    const float* exemplar_labels = (const float*)d_in[2];
    const float* exemplar_sizes  = (const float*)d_in[3];
    const float* average_label   = (const float*)d_in[4];
    const float* tau_squared     = (const float*)d_in[5];
    const float* gamma_n         = (const float*)d_in[6];
    float* out = (float*)d_out;

    knn_weighted_gather_kernel<<<BQ / QPB, QPB * 64, 0, stream>>>(
        sq_dists, labels, exemplar_labels, exemplar_sizes, average_label,
        tau_squared, gamma_n, out);
}

// Round 5
// 26.824 us; speedup vs baseline: 1.5202x; 1.0176x over previous
//
#include <hip/hip_runtime.h>
#include <hip/hip_bf16.h>

// Problem constants (match reference)
#define BQ 4096
#define KN 64
#define KH 32   // k's per wave (query split across 2 waves)
#define LD 256

__global__ __launch_bounds__(256, 8) void knn_weighted_gather_kernel(
    const float* __restrict__ sq_dists,       // [B, K]
    const int*   __restrict__ labels,         // [B, K]
    const float* __restrict__ exemplar_labels,// [N, L]
    const float* __restrict__ exemplar_sizes, // [N]
    const float* __restrict__ average_label,  // [L]
    const float* __restrict__ tau_squared_p,  // [1]
    const float* __restrict__ gamma_n_p,      // [1]
    float* __restrict__ out)                  // [B, L] f32
{
    __shared__ float4 s_acc[2][64];
    __shared__ float  s_den[2];

    const int wave = threadIdx.x >> 6;   // 0..3
    const int lane = threadIdx.x & 63;
    const int qloc = wave >> 1;          // 0..1: query within block
    const int h    = wave & 1;           // 0..1: k-half within query
    const int q    = blockIdx.x * 2 + qloc;

    const float tau2    = tau_squared_p[0];
    const float gamma_n = gamma_n_p[0];

    // This wave owns k in [h*32, h*32+32). Duplicate into both 32-lane halves
    // so ballot bits 0..31, readlane, and the reduce all see the same data.
    const int kk = h * KH + (lane & (KH - 1));
    float d   = sq_dists[q * KN + kk];
    int   lab = labels  [q * KN + kk];
    float w   = (d <= tau2) ? __expf(-d) : 0.0f;

    // Partial denominator: reduce 32 distinct values within each half.
    float dpart = w * exemplar_sizes[lab];
    #pragma unroll
    for (int off = KH / 2; off > 0; off >>= 1)
        dpart += __shfl_xor(dpart, off, 64);
    // dpart = sum over this wave's 32 k's (identical in both halves).

    // Compact active k's: low 32 ballot bits <-> lanes 0..31 <-> this wave's k's.
    unsigned long long mask = __ballot(w != 0.0f) & 0xFFFFFFFFull;
    const int nact = __popcll(mask);
    const int wbits = __float_as_int(w);
    const float* __restrict__ colbase = exemplar_labels + lane * 4;

    float4 acc = make_float4(0.f, 0.f, 0.f, 0.f);

#define STEP(SV, WV, LV, VV)                                          \
    int SV = (int)__builtin_ctzll(mask); mask &= mask - 1;            \
    float WV = __int_as_float(__builtin_amdgcn_readlane(wbits, SV));  \
    int LV = __builtin_amdgcn_readlane(lab, SV);                      \
    const float4 VV = *reinterpret_cast<const float4*>(colbase + (size_t)LV * LD)

#define FMA4(WV, VV)                                                  \
    acc.x += WV * VV.x; acc.y += WV * VV.y;                           \
    acc.z += WV * VV.z; acc.w += WV * VV.w

    int i = 0;
    for (; i + 8 <= nact; i += 8) {
        STEP(s0, w0, l0, v0); STEP(s1, w1, l1, v1);
        STEP(s2, w2, l2, v2); STEP(s3, w3, l3, v3);
        STEP(s4, w4, l4, v4); STEP(s5, w5, l5, v5);
        STEP(s6, w6, l6, v6); STEP(s7, w7, l7, v7);
        FMA4(w0, v0); FMA4(w1, v1); FMA4(w2, v2); FMA4(w3, v3);
        FMA4(w4, v4); FMA4(w5, v5); FMA4(w6, v6); FMA4(w7, v7);
    }
    for (; i < nact; ++i) {
        STEP(s0, w0, l0, v0);
        FMA4(w0, v0);
    }
#undef STEP
#undef FMA4

    // Combine the two half-query waves through LDS.
    if (h == 1) {
        s_acc[qloc][lane] = acc;
        if (lane == 0) s_den[qloc] = dpart;
    }
    __syncthreads();
    if (h == 0) {
        const float4 o = s_acc[qloc][lane];
        acc.x += o.x; acc.y += o.y; acc.z += o.z; acc.w += o.w;
        const float den = dpart + s_den[qloc] + gamma_n;
        const float inv = 1.0f / den;
        const float4 avg = *reinterpret_cast<const float4*>(average_label + lane * 4);
        float4 res;
        res.x = (acc.x + gamma_n * avg.x) * inv;
        res.y = (acc.y + gamma_n * avg.y) * inv;
        res.z = (acc.z + gamma_n * avg.z) * inv;
        res.w = (acc.w + gamma_n * avg.w) * inv;
        *reinterpret_cast<float4*>(out + (size_t)q * LD + lane * 4) = res;
    }
}

extern "C" void kernel_launch(void* const* d_in, const int* in_sizes, int n_in,
                              void* d_out, int out_size, void* d_ws, size_t ws_size,
                              hipStream_t stream) {
    const float* sq_dists        = (const float*)d_in[0];
    const int*   labels          = (const int*)  d_in[1];
    const float* exemplar_labels = (const float*)d_in[2];
    const float* exemplar_sizes  = (const float*)d_in[3];
    const float* average_label   = (const float*)d_in[4];
    const float* tau_squared     = (const float*)d_in[5];
    const float* gamma_n         = (const float*)d_in[6];
    float* out = (float*)d_out;

    knn_weighted_gather_kernel<<<BQ / 2, 256, 0, stream>>>(
        sq_dists, labels, exemplar_labels, exemplar_sizes, average_label,
        tau_squared, gamma_n, out);
}